// Round 5
// baseline (268.524 us; speedup 1.0000x reference)
//
#include <hip/hip_runtime.h>

#define HID 32
#define MIN_WEIGHT -100000.0f

// ---------------------------------------------------------------------------
// Node-stage kernel, register-blocked: block = 256 threads = 4 waves.
//   lane l (0..63)    : 4 nodes each (node = blk*256 + q*64 + l, q=0..3)
//   wave w = oct      : 8 of the 32 output columns (wave-uniform -> s_load W)
// Phase A: acc[q][t] += row_q[j] * W[j][oct*8+t]; W slice is ONE s_load_dwordx8
//          per j reused by 4 nodes x 8 cols = 32 FMAs (was 1 load : 1 FMA).
// Phase B: relu -> LDS g[256][33] (pad 33: bank (l+j)%32, conflict-free).
// Phase C: p = g @ P0 (and @ P1 if TWO), same register-blocked pattern.
template <int ROW, bool TWO>
__global__ __launch_bounds__(256) void nodek(
    const float* __restrict__ emb, const int* __restrict__ n_map,
    const int* __restrict__ sel, const float* __restrict__ W,
    const float* __restrict__ P0, const float* __restrict__ P1,
    float* __restrict__ o0, float* __restrict__ o1, int n) {
    constexpr int NPT = 4;
    __shared__ float gl[256 * 33];  // 33.8 KB

    const int l = threadIdx.x & 63;
    const int oct = __builtin_amdgcn_readfirstlane(threadIdx.x >> 6);
    const int base = blockIdx.x * 256;

    const float* rp[NPT];
    int nd[NPT];
#pragma unroll
    for (int q = 0; q < NPT; ++q) {
        int node = base + q * 64 + l;
        nd[q] = node;
        int cn = node < n ? node : n - 1;  // clamp, keep lanes active
        int local = sel ? sel[cn] : cn;
        rp[q] = emb + (size_t)n_map[local] * ROW;
    }

    float acc[NPT][8];
#pragma unroll
    for (int q = 0; q < NPT; ++q)
#pragma unroll
        for (int t = 0; t < 8; ++t) acc[q][t] = 0.f;

    const float* Wo = W + oct * 8;  // wave-uniform column slice
#pragma unroll 2
    for (int j0 = 0; j0 < ROW; j0 += 4) {
        float rr[NPT][4];
#pragma unroll
        for (int q = 0; q < NPT; ++q) {
            float4 r4 = *(const float4*)(rp[q] + j0);  // per-lane gather
            rr[q][0] = r4.x; rr[q][1] = r4.y; rr[q][2] = r4.z; rr[q][3] = r4.w;
        }
#pragma unroll
        for (int jj = 0; jj < 4; ++jj) {
            const float* wr = Wo + (size_t)(j0 + jj) * HID;
            float w8[8];
#pragma unroll
            for (int t = 0; t < 8; ++t) w8[t] = wr[t];  // uniform -> s_load
#pragma unroll
            for (int q = 0; q < NPT; ++q)
#pragma unroll
                for (int t = 0; t < 8; ++t)
                    acc[q][t] = fmaf(rr[q][jj], w8[t], acc[q][t]);
        }
    }

    // ---- phase B: relu -> LDS exchange ------------------------------------
#pragma unroll
    for (int q = 0; q < NPT; ++q)
#pragma unroll
        for (int t = 0; t < 8; ++t)
            gl[(q * 64 + l) * 33 + oct * 8 + t] = fmaxf(acc[q][t], 0.f);
    __syncthreads();

    // ---- phase C: projections, register-blocked the same way --------------
    float p0[NPT][8], p1[NPT][8];
#pragma unroll
    for (int q = 0; q < NPT; ++q)
#pragma unroll
        for (int t = 0; t < 8; ++t) { p0[q][t] = 0.f; p1[q][t] = 0.f; }
    const float* Q0 = P0 + oct * 8;
    const float* Q1 = TWO ? (P1 + oct * 8) : Q0;
#pragma unroll 8
    for (int j = 0; j < HID; ++j) {
        float w8a[8], w8b[8];
#pragma unroll
        for (int t = 0; t < 8; ++t) w8a[t] = Q0[(size_t)j * HID + t];
        if (TWO) {
#pragma unroll
            for (int t = 0; t < 8; ++t) w8b[t] = Q1[(size_t)j * HID + t];
        }
#pragma unroll
        for (int q = 0; q < NPT; ++q) {
            float gv = gl[(q * 64 + l) * 33 + j];  // bank (l+j)%32, free
#pragma unroll
            for (int t = 0; t < 8; ++t) p0[q][t] = fmaf(gv, w8a[t], p0[q][t]);
            if (TWO) {
#pragma unroll
                for (int t = 0; t < 8; ++t) p1[q][t] = fmaf(gv, w8b[t], p1[q][t]);
            }
        }
    }

#pragma unroll
    for (int q = 0; q < NPT; ++q) {
        if (nd[q] < n) {
            float* d0 = o0 + (size_t)nd[q] * HID + oct * 8;
            float4 va = {p0[q][0], p0[q][1], p0[q][2], p0[q][3]};
            float4 vb = {p0[q][4], p0[q][5], p0[q][6], p0[q][7]};
            *(float4*)(d0 + 0) = va;
            *(float4*)(d0 + 4) = vb;
            if (TWO) {
                float* d1 = o1 + (size_t)nd[q] * HID + oct * 8;
                float4 wa = {p1[q][0], p1[q][1], p1[q][2], p1[q][3]};
                float4 wb = {p1[q][4], p1[q][5], p1[q][6], p1[q][7]};
                *(float4*)(d1 + 0) = wa;
                *(float4*)(d1 + 4) = wb;
            }
        }
    }
}

// ---------------------------------------------------------------------------
// Merged edge kernel: thread i < H1 -> one-hop (att slab 1), else two-hop
// (att slab 0). The hop index sets partition [0,E), so each edge writes its
// att to one slab and MIN_WEIGHT to the other -> full d_out coverage.
__global__ __launch_bounds__(256) void edgek(
    const int* __restrict__ one_hop, int H1, const int* __restrict__ two_hop,
    int H2, const int* __restrict__ src, const int* __restrict__ dst,
    const int* __restrict__ e_batch, const float* __restrict__ a1,
    const float* __restrict__ b2, const float* __restrict__ a0,
    const float* __restrict__ b1, const float* __restrict__ t2,
    const float* __restrict__ be1, const float* __restrict__ We2,
    const float* __restrict__ be2, float* __restrict__ out, int E) {
    int i = blockIdx.x * blockDim.x + threadIdx.x;
    const float *SA, *DB;
    float *oatt, *omin;
    int e;
    if (i < H1) {
        e = one_hop[i]; SA = a1; DB = b2; oatt = out + (size_t)E; omin = out;
    } else {
        int k = i - H1;
        if (k >= H2) return;
        e = two_hop[k]; SA = a0; DB = b1; oatt = out; omin = out + (size_t)E;
    }
    const float* sv = SA + (size_t)src[e] * HID;
    const float* dv = DB + (size_t)dst[e] * HID;
    const float* tv = t2 + (size_t)e_batch[e] * HID;
    float att = be2[0];
#pragma unroll
    for (int k = 0; k < HID; k += 4) {
        float4 s4 = *(const float4*)(sv + k);
        float4 d4 = *(const float4*)(dv + k);
        float4 t4 = *(const float4*)(tv + k);
        float h;
        h = fmaxf(s4.x + d4.x + t4.x + be1[k + 0], 0.f); att = fmaf(h, We2[k + 0], att);
        h = fmaxf(s4.y + d4.y + t4.y + be1[k + 1], 0.f); att = fmaf(h, We2[k + 1], att);
        h = fmaxf(s4.z + d4.z + t4.z + be1[k + 2], 0.f); att = fmaf(h, We2[k + 2], att);
        h = fmaxf(s4.w + d4.w + t4.w + be1[k + 3], 0.f); att = fmaf(h, We2[k + 3], att);
    }
    oatt[e] = att;
    omin[e] = MIN_WEIGHT;
}

// ---------------------------------------------------------------------------
extern "C" void kernel_launch(void* const* d_in, const int* in_sizes, int n_in,
                              void* d_out, int out_size, void* d_ws, size_t ws_size,
                              hipStream_t stream) {
    const float* emb0 = (const float*)d_in[0];
    const float* emb1 = (const float*)d_in[1];
    const float* emb2 = (const float*)d_in[2];
    const int* n_map = (const int*)d_in[3];
    const int* src = (const int*)d_in[4];
    const int* dst = (const int*)d_in[5];
    const int* e_batch = (const int*)d_in[6];
    const int* offset_node = (const int*)d_in[7];
    const int* one_hop = (const int*)d_in[8];
    const int* two_hop = (const int*)d_in[9];
    const float* W0 = (const float*)d_in[10];
    const float* W1 = (const float*)d_in[11];
    const float* W2 = (const float*)d_in[12];
    const float* We1 = (const float*)d_in[13];
    const float* be1 = (const float*)d_in[14];
    const float* We2 = (const float*)d_in[15];
    const float* be2 = (const float*)d_in[16];

    const int n_nodes = in_sizes[3];
    const int E = in_sizes[4];
    const int batch = in_sizes[7];
    const int H1 = in_sizes[8];  // one-hop edge count
    const int H2 = in_sizes[9];  // two-hop edge count

    float* out = (float*)d_out;

    const float* A = We1;             // rows 0..31   (multiplies s)
    const float* B = We1 + 32 * HID;  // rows 32..63  (multiplies d)
    const float* T = We1 + 64 * HID;  // rows 64..95  (multiplies t)

    // workspace layout: a0 | a1 | b1 | b2 | t2
    float* a0 = (float*)d_ws;
    float* a1 = a0 + (size_t)n_nodes * HID;
    float* b1 = a1 + (size_t)n_nodes * HID;
    float* b2 = b1 + (size_t)n_nodes * HID;
    float* t2 = b2 + (size_t)n_nodes * HID;

    const int nblk = (n_nodes + 255) / 256;
    // a0 = relu(emb0@W0)@A
    nodek<128, false><<<nblk, 256, 0, stream>>>(
        emb0, n_map, nullptr, W0, A, nullptr, a0, nullptr, n_nodes);
    // a1 = relu(emb1@W1)@A ; b1 = relu(emb1@W1)@B
    nodek<256, true><<<nblk, 256, 0, stream>>>(
        emb1, n_map, nullptr, W1, A, B, a1, b1, n_nodes);
    // b2 = relu(emb2@W2)@B
    nodek<64, false><<<nblk, 256, 0, stream>>>(
        emb2, n_map, nullptr, W2, B, nullptr, b2, nullptr, n_nodes);
    // t2 = relu(emb2[n_map[offset_node]]@W2)@T
    nodek<64, false><<<(batch + 255) / 256, 256, 0, stream>>>(
        emb2, n_map, offset_node, W2, T, nullptr, t2, nullptr, batch);

    // merged edge stage
    edgek<<<(H1 + H2 + 255) / 256, 256, 0, stream>>>(
        one_hop, H1, two_hop, H2, src, dst, e_batch, a1, b2, a0, b1, t2,
        be1, We2, be2, out, E);
}